// Round 4
// baseline (155.333 us; speedup 1.0000x reference)
//
#include <hip/hip_runtime.h>
#include <hip/hip_bf16.h>

__device__ __forceinline__ float sigm(float x) { return 1.0f / (1.0f + __expf(-x)); }

// Fused FRAP forward, float32 I/O. i-major mapping: blockIdx -> (i, bp-chunk),
// one thread per output (bp, i). All 7 xf vectors register-blocked; W (w_comb
// with relu(yc) folded, both mask variants) read once per thread in the q-loop
// and selected per (q,j) via a block-uniform scalar branch (mask depends only
// on (i,j), and i is uniform per block).
__global__ __launch_bounds__(256, 2) void frap_fused(
    const float* __restrict__ feat,      // B*16
    const float* __restrict__ emb_phase, // 8
    const float* __restrict__ w_veh,     // 4
    const float* __restrict__ b_veh,     // 4
    const float* __restrict__ w_line,    // 128
    const float* __restrict__ b_line,    // 16
    const float* __restrict__ emb_const, // 8
    const float* __restrict__ w_feat,    // 640
    const float* __restrict__ b_feat,    // 20
    const float* __restrict__ w_const,   // 80
    const float* __restrict__ b_const,   // 20
    const float* __restrict__ w_comb,    // 400
    const float* __restrict__ b_comb,    // 20
    const float* __restrict__ w_final,   // 20
    const float* __restrict__ b_final,   // 1
    const int*  __restrict__ cmask,      // 56
    float* __restrict__ out,             // B*8
    int B, int bpi)                      // bpi = blocks per i
{
    __shared__ __align__(16) float s_ya[60 * 20];
    __shared__ __align__(16) float s_yb[60 * 20];
    __shared__ __align__(16) float s_wcm[2 * 20 * 20];
    __shared__ float s_stage[820];   // [0,128)=w_line [128,768)=w_feat [768,784)=b_line
                                     // [784,788)=w_veh [788,792)=b_veh [792,800)=emb_phase [800,820)=b_feat
    __shared__ float s_bcomb[20], s_wfin[20];
    __shared__ unsigned s_maskbits[8];
    __shared__ float s_bfin;

    const int tid = threadIdx.x;

    // ---- stage tiny weights ----
    for (int k = tid; k < 128; k += 256) s_stage[k] = w_line[k];
    for (int k = tid; k < 640; k += 256) s_stage[128 + k] = w_feat[k];
    if (tid < 16)                s_stage[768 + tid] = b_line[tid];
    if (tid < 4)                 s_stage[784 + tid] = w_veh[tid];
    if (tid >= 4 && tid < 8)     s_stage[784 + tid] = b_veh[tid - 4];
    if (tid >= 8 && tid < 16)    s_stage[784 + tid] = emb_phase[tid - 8];
    if (tid >= 16 && tid < 36)   s_stage[784 + tid] = b_feat[tid - 16];
    __syncthreads();

    // ---- build YA/YB tables: 240 threads, 4 per key (5 outputs each) ----
    if (tid < 240) {
        int key = tid >> 2, part = tid & 3;
        int veh = key >> 1, pb = key & 1;
        float vf = (float)veh;
        float line[8];
#pragma unroll
        for (int k = 0; k < 4; k++) line[k] = sigm(fmaf(vf, s_stage[784 + k], s_stage[788 + k]));
#pragma unroll
        for (int k = 0; k < 4; k++) line[4 + k] = sigm(s_stage[792 + pb * 4 + k]);
        float X[16];
#pragma unroll
        for (int o = 0; o < 16; o++) {
            float x = s_stage[768 + o];
#pragma unroll
            for (int d = 0; d < 8; d++) x = fmaf(line[d], s_stage[o * 8 + d], x);
            X[o] = fmaxf(x, 0.f);
        }
        int o0 = part * 5;
#pragma unroll
        for (int oo = 0; oo < 5; oo++) {
            int o = o0 + oo;
            float a = 0.25f * s_stage[800 + o];
            float bb = a;
#pragma unroll
            for (int c = 0; c < 16; c++) {
                a  = fmaf(X[c], s_stage[128 + o * 32 + c], a);
                bb = fmaf(X[c], s_stage[128 + o * 32 + 16 + c], bb);
            }
            s_ya[key * 20 + o] = a;
            s_yb[key * 20 + o] = bb;
        }
    }

    // ---- build WCM (w_comb with relu(yc) folded) ----
    for (int idx = tid; idx < 800; idx += 256) {
        int m = idx / 400;
        int r = idx - m * 400;
        int q = r / 20;
        int o = r - q * 20;
        float yc = b_const[o];
#pragma unroll
        for (int k = 0; k < 4; k++)
            yc = fmaf(w_const[o * 4 + k], emb_const[m * 4 + k], yc);
        s_wcm[idx] = w_comb[q * 20 + o] * fmaxf(yc, 0.f);
    }
    if (tid < 20) { s_bcomb[tid] = b_comb[tid]; s_wfin[tid] = w_final[tid]; }
    if (tid < 8) {
        unsigned mb = 0;
        for (int j = 0; j < 7; j++) mb |= ((unsigned)cmask[tid * 7 + j] & 1u) << j;
        s_maskbits[tid] = mb;
    }
    if (tid == 0) s_bfin = b_final[0];
    __syncthreads();

    // ---- main: i-major; i uniform per block ----
    int i = blockIdx.x / bpi;
    int blk = blockIdx.x - i * bpi;
    int bp = blk * 256 + tid;
    if (bp >= B) return;
    unsigned mrow = __builtin_amdgcn_readfirstlane(s_maskbits[i]);

    const unsigned Bu = (unsigned)B;
    unsigned g = (unsigned)bp * 56u + (unsigned)i * 7u;
    unsigned p = g / Bu;
    unsigned b = g - p * Bu;

    const unsigned L0T = 0x64204051u, L1T = 0x75316273u;
    unsigned pi = p / 7u;
    unsigned c7 = p - pi * 7u;
    unsigned pj = c7 + (c7 >= pi ? 1u : 0u);
    int la0 = (L0T >> (pi * 4)) & 15, la1 = (L1T >> (pi * 4)) & 15;
    int lb0 = (L0T >> (pj * 4)) & 15, lb1 = (L1T >> (pj * 4)) & 15;

    // ---- phase 1: build all 7 xf vectors in registers ----
    float xf[7][20];
#pragma unroll
    for (int j = 0; j < 7; j++) {
        if (b >= Bu) {
            b -= Bu;
            p++;
            pi = p / 7u;
            c7 = p - pi * 7u;
            pj = c7 + (c7 >= pi ? 1u : 0u);
            la0 = (L0T >> (pi * 4)) & 15; la1 = (L1T >> (pi * 4)) & 15;
            lb0 = (L0T >> (pj * 4)) & 15; lb1 = (L1T >> (pj * 4)) & 15;
        }
        const float* row = feat + (size_t)b * 16;
        float bA0 = row[la0], vA0 = row[8 + la0];
        float bA1 = row[la1], vA1 = row[8 + la1];
        float bB0 = row[lb0], vB0 = row[8 + lb0];
        float bB1 = row[lb1], vB1 = row[8 + lb1];
        int kA0 = (int)fmaf(vA0, 2.f, bA0);
        int kA1 = (int)fmaf(vA1, 2.f, bA1);
        int kB0 = (int)fmaf(vB0, 2.f, bB0);
        int kB1 = (int)fmaf(vB1, 2.f, bB1);
        kA0 = min(59, max(0, kA0)); kA1 = min(59, max(0, kA1));
        kB0 = min(59, max(0, kB0)); kB1 = min(59, max(0, kB1));

        const float4* A0 = (const float4*)(s_ya + kA0 * 20);
        const float4* A1 = (const float4*)(s_ya + kA1 * 20);
        const float4* B0 = (const float4*)(s_yb + kB0 * 20);
        const float4* B1 = (const float4*)(s_yb + kB1 * 20);
#pragma unroll
        for (int r = 0; r < 5; r++) {
            float4 a0 = A0[r], a1 = A1[r], c0 = B0[r], c1 = B1[r];
            xf[j][4 * r + 0] = fmaxf(a0.x + a1.x + c0.x + c1.x, 0.f);
            xf[j][4 * r + 1] = fmaxf(a0.y + a1.y + c0.y + c1.y, 0.f);
            xf[j][4 * r + 2] = fmaxf(a0.z + a1.z + c0.z + c1.z, 0.f);
            xf[j][4 * r + 3] = fmaxf(a0.w + a1.w + c0.w + c1.w, 0.f);
        }
        b++;
    }

    // ---- phase 2: q-loop, W rows read once, uniform-branch select per j ----
    float acc[7];
#pragma unroll
    for (int j = 0; j < 7; j++) acc[j] = 0.f;

    for (int q = 0; q < 20; q++) {
        const float4* w0p = (const float4*)(s_wcm + q * 20);
        const float4* w1p = (const float4*)(s_wcm + 400 + q * 20);
        float4 u0 = w0p[0], u1 = w0p[1], u2 = w0p[2], u3 = w0p[3], u4 = w0p[4];
        float4 v0 = w1p[0], v1 = w1p[1], v2 = w1p[2], v3 = w1p[3], v4 = w1p[4];
        float bq = s_bcomb[q], wq = s_wfin[q];
#pragma unroll
        for (int j = 0; j < 7; j++) {
            float h = bq;
            if (mrow & (1u << j)) {
                h = fmaf(v0.x, xf[j][0],  h); h = fmaf(v0.y, xf[j][1],  h);
                h = fmaf(v0.z, xf[j][2],  h); h = fmaf(v0.w, xf[j][3],  h);
                h = fmaf(v1.x, xf[j][4],  h); h = fmaf(v1.y, xf[j][5],  h);
                h = fmaf(v1.z, xf[j][6],  h); h = fmaf(v1.w, xf[j][7],  h);
                h = fmaf(v2.x, xf[j][8],  h); h = fmaf(v2.y, xf[j][9],  h);
                h = fmaf(v2.z, xf[j][10], h); h = fmaf(v2.w, xf[j][11], h);
                h = fmaf(v3.x, xf[j][12], h); h = fmaf(v3.y, xf[j][13], h);
                h = fmaf(v3.z, xf[j][14], h); h = fmaf(v3.w, xf[j][15], h);
                h = fmaf(v4.x, xf[j][16], h); h = fmaf(v4.y, xf[j][17], h);
                h = fmaf(v4.z, xf[j][18], h); h = fmaf(v4.w, xf[j][19], h);
            } else {
                h = fmaf(u0.x, xf[j][0],  h); h = fmaf(u0.y, xf[j][1],  h);
                h = fmaf(u0.z, xf[j][2],  h); h = fmaf(u0.w, xf[j][3],  h);
                h = fmaf(u1.x, xf[j][4],  h); h = fmaf(u1.y, xf[j][5],  h);
                h = fmaf(u1.z, xf[j][6],  h); h = fmaf(u1.w, xf[j][7],  h);
                h = fmaf(u2.x, xf[j][8],  h); h = fmaf(u2.y, xf[j][9],  h);
                h = fmaf(u2.z, xf[j][10], h); h = fmaf(u2.w, xf[j][11], h);
                h = fmaf(u3.x, xf[j][12], h); h = fmaf(u3.y, xf[j][13], h);
                h = fmaf(u3.z, xf[j][14], h); h = fmaf(u3.w, xf[j][15], h);
                h = fmaf(u4.x, xf[j][16], h); h = fmaf(u4.y, xf[j][17], h);
                h = fmaf(u4.z, xf[j][18], h); h = fmaf(u4.w, xf[j][19], h);
            }
            acc[j] = fmaf(wq, fmaxf(h, 0.f), acc[j]);
        }
    }

    float total = 0.f;
    float bfin = s_bfin;
#pragma unroll
    for (int j = 0; j < 7; j++) total += fmaxf(acc[j] + bfin, 0.f);

    out[(size_t)bp * 8 + i] = total;
}

extern "C" void kernel_launch(void* const* d_in, const int* in_sizes, int n_in,
                              void* d_out, int out_size, void* d_ws, size_t ws_size,
                              hipStream_t stream) {
    const float* feat      = (const float*)d_in[0];
    const float* emb_phase = (const float*)d_in[1];
    const float* w_veh     = (const float*)d_in[2];
    const float* b_veh     = (const float*)d_in[3];
    const float* w_line    = (const float*)d_in[4];
    const float* b_line    = (const float*)d_in[5];
    const float* emb_const = (const float*)d_in[6];
    const float* w_feat    = (const float*)d_in[7];
    const float* b_feat    = (const float*)d_in[8];
    const float* w_const   = (const float*)d_in[9];
    const float* b_const   = (const float*)d_in[10];
    const float* w_comb    = (const float*)d_in[11];
    const float* b_comb    = (const float*)d_in[12];
    const float* w_final   = (const float*)d_in[13];
    const float* b_final   = (const float*)d_in[14];
    const int*   cmask     = (const int*)d_in[15];

    int B = in_sizes[0] / 16;            // 16384
    int bpi = (B + 255) / 256;           // blocks per i (64)
    int blocks = 8 * bpi;                // 512
    frap_fused<<<blocks, 256, 0, stream>>>(feat, emb_phase, w_veh, b_veh,
                                           w_line, b_line, emb_const, w_feat,
                                           b_feat, w_const, b_const, w_comb,
                                           b_comb, w_final, b_final, cmask,
                                           (float*)d_out, B, bpi);
}

// Round 6
// 120.810 us; speedup vs baseline: 1.2858x; 1.2858x over previous
//
#include <hip/hip_runtime.h>
#include <hip/hip_bf16.h>

__device__ __forceinline__ float sigm(float x) { return 1.0f / (1.0f + __expf(-x)); }

// Fused FRAP forward, float32 I/O.
// 512-thread blocks = 8 waves; wave k handles phase i=k for 64 consecutive bp.
// mrow (constant_mask row) is wave-uniform -> scalar branches + uniform W reads.
// xf register-blocked in two groups {4,3} to stay under the VGPR cliff; W
// (w_comb with relu(yc) folded, both variants) read once per q per group as
// uniform-address float4 broadcasts.
__global__ __launch_bounds__(512, 2) void frap_fused(
    const float* __restrict__ feat,      // B*16
    const float* __restrict__ emb_phase, // 8
    const float* __restrict__ w_veh,     // 4
    const float* __restrict__ b_veh,     // 4
    const float* __restrict__ w_line,    // 128
    const float* __restrict__ b_line,    // 16
    const float* __restrict__ emb_const, // 8
    const float* __restrict__ w_feat,    // 640
    const float* __restrict__ b_feat,    // 20
    const float* __restrict__ w_const,   // 80
    const float* __restrict__ b_const,   // 20
    const float* __restrict__ w_comb,    // 400
    const float* __restrict__ b_comb,    // 20
    const float* __restrict__ w_final,   // 20
    const float* __restrict__ b_final,   // 1
    const int*  __restrict__ cmask,      // 56
    float* __restrict__ out,             // B*8
    int B)
{
    __shared__ __align__(16) float s_ya[60 * 20];
    __shared__ __align__(16) float s_yb[60 * 20];
    __shared__ __align__(16) float s_wcm[2 * 20 * 20];
    __shared__ float s_stage[820];   // [0,128)=w_line [128,768)=w_feat [768,784)=b_line
                                     // [784,788)=w_veh [788,792)=b_veh [792,800)=emb_phase [800,820)=b_feat
    __shared__ float s_bcomb[20], s_wfin[20];
    __shared__ unsigned s_maskbits[8];
    __shared__ float s_bfin;

    const int tid = threadIdx.x;

    // ---- stage tiny weights ----
    for (int k = tid; k < 128; k += 512) s_stage[k] = w_line[k];
    for (int k = tid; k < 640; k += 512) s_stage[128 + k] = w_feat[k];
    if (tid < 16)                s_stage[768 + tid] = b_line[tid];
    if (tid < 4)                 s_stage[784 + tid] = w_veh[tid];
    if (tid >= 4 && tid < 8)     s_stage[784 + tid] = b_veh[tid - 4];
    if (tid >= 8 && tid < 16)    s_stage[784 + tid] = emb_phase[tid - 8];
    if (tid >= 16 && tid < 36)   s_stage[784 + tid] = b_feat[tid - 16];
    __syncthreads();

    // ---- build YA/YB tables: 240 threads, 4 per key (5 outputs each) ----
    if (tid < 240) {
        int key = tid >> 2, part = tid & 3;
        int veh = key >> 1, pb = key & 1;
        float vf = (float)veh;
        float line[8];
#pragma unroll
        for (int k = 0; k < 4; k++) line[k] = sigm(fmaf(vf, s_stage[784 + k], s_stage[788 + k]));
#pragma unroll
        for (int k = 0; k < 4; k++) line[4 + k] = sigm(s_stage[792 + pb * 4 + k]);
        float X[16];
#pragma unroll
        for (int o = 0; o < 16; o++) {
            float x = s_stage[768 + o];
#pragma unroll
            for (int d = 0; d < 8; d++) x = fmaf(line[d], s_stage[o * 8 + d], x);
            X[o] = fmaxf(x, 0.f);
        }
        int o0 = part * 5;
#pragma unroll
        for (int oo = 0; oo < 5; oo++) {
            int o = o0 + oo;
            float a = 0.25f * s_stage[800 + o];
            float bb = a;
#pragma unroll
            for (int c = 0; c < 16; c++) {
                a  = fmaf(X[c], s_stage[128 + o * 32 + c], a);
                bb = fmaf(X[c], s_stage[128 + o * 32 + 16 + c], bb);
            }
            s_ya[key * 20 + o] = a;
            s_yb[key * 20 + o] = bb;
        }
    }

    // ---- build WCM (w_comb with relu(yc) folded) ----
    for (int idx = tid; idx < 800; idx += 512) {
        int m = idx / 400;
        int r = idx - m * 400;
        int q = r / 20;
        int o = r - q * 20;
        float yc = b_const[o];
#pragma unroll
        for (int k = 0; k < 4; k++)
            yc = fmaf(w_const[o * 4 + k], emb_const[m * 4 + k], yc);
        s_wcm[idx] = w_comb[q * 20 + o] * fmaxf(yc, 0.f);
    }
    if (tid < 20) { s_bcomb[tid] = b_comb[tid]; s_wfin[tid] = w_final[tid]; }
    if (tid < 8) {
        unsigned mb = 0;
        for (int j = 0; j < 7; j++) mb |= ((unsigned)cmask[tid * 7 + j] & 1u) << j;
        s_maskbits[tid] = mb;
    }
    if (tid == 0) s_bfin = b_final[0];
    __syncthreads();

    // ---- main ----
    const int lane = tid & 63;
    const int i = tid >> 6;                       // wave id == phase i (uniform per wave)
    const int bp = (blockIdx.x << 6) + lane;
    if (bp >= B) return;

    const unsigned mrow = __builtin_amdgcn_readfirstlane(s_maskbits[i]);
    const unsigned Bu = (unsigned)B;
    unsigned g = 56u * (unsigned)bp + 7u * (unsigned)i;
    unsigned p = g / Bu;
    unsigned b = g - p * Bu;

    const unsigned L0T = 0x64204051u, L1T = 0x75316273u;
    unsigned pi = p / 7u;
    unsigned c7 = p - pi * 7u;
    unsigned pj = c7 + (c7 >= pi ? 1u : 0u);
    int la0 = (L0T >> (pi * 4)) & 15, la1 = (L1T >> (pi * 4)) & 15;
    int lb0 = (L0T >> (pj * 4)) & 15, lb1 = (L1T >> (pj * 4)) & 15;

#define BUILD_XF(dst)                                                          \
    do {                                                                       \
        if (b >= Bu) {                                                         \
            b -= Bu; p++;                                                      \
            pi = p / 7u; c7 = p - pi * 7u;                                     \
            pj = c7 + (c7 >= pi ? 1u : 0u);                                    \
            la0 = (L0T >> (pi * 4)) & 15; la1 = (L1T >> (pi * 4)) & 15;        \
            lb0 = (L0T >> (pj * 4)) & 15; lb1 = (L1T >> (pj * 4)) & 15;        \
        }                                                                      \
        const float* row = feat + (size_t)b * 16;                              \
        float bA0 = row[la0], vA0 = row[8 + la0];                              \
        float bA1 = row[la1], vA1 = row[8 + la1];                              \
        float bB0 = row[lb0], vB0 = row[8 + lb0];                              \
        float bB1 = row[lb1], vB1 = row[8 + lb1];                              \
        int kA0 = (int)fmaf(vA0, 2.f, bA0);                                    \
        int kA1 = (int)fmaf(vA1, 2.f, bA1);                                    \
        int kB0 = (int)fmaf(vB0, 2.f, bB0);                                    \
        int kB1 = (int)fmaf(vB1, 2.f, bB1);                                    \
        kA0 = min(59, max(0, kA0)); kA1 = min(59, max(0, kA1));                \
        kB0 = min(59, max(0, kB0)); kB1 = min(59, max(0, kB1));                \
        const float4* A0 = (const float4*)(s_ya + kA0 * 20);                   \
        const float4* A1 = (const float4*)(s_ya + kA1 * 20);                   \
        const float4* B0 = (const float4*)(s_yb + kB0 * 20);                   \
        const float4* B1 = (const float4*)(s_yb + kB1 * 20);                   \
        _Pragma("unroll")                                                      \
        for (int r = 0; r < 5; r++) {                                          \
            float4 a0 = A0[r], a1 = A1[r], c0 = B0[r], c1 = B1[r];             \
            dst[4 * r + 0] = fmaxf(a0.x + a1.x + c0.x + c1.x, 0.f);            \
            dst[4 * r + 1] = fmaxf(a0.y + a1.y + c0.y + c1.y, 0.f);            \
            dst[4 * r + 2] = fmaxf(a0.z + a1.z + c0.z + c1.z, 0.f);            \
            dst[4 * r + 3] = fmaxf(a0.w + a1.w + c0.w + c1.w, 0.f);            \
        }                                                                      \
        b++;                                                                   \
    } while (0)

// NOTE: data param is named Xv (NOT x) so it cannot collide with the .x/.y/.z/.w
// member-access tokens during macro substitution (round-5 compile failure).
#define DOT20(h, w0, w1, w2, w3, w4, Xv)                                       \
    h = fmaf(w0.x, Xv[0],  h); h = fmaf(w0.y, Xv[1],  h);                      \
    h = fmaf(w0.z, Xv[2],  h); h = fmaf(w0.w, Xv[3],  h);                      \
    h = fmaf(w1.x, Xv[4],  h); h = fmaf(w1.y, Xv[5],  h);                      \
    h = fmaf(w1.z, Xv[6],  h); h = fmaf(w1.w, Xv[7],  h);                      \
    h = fmaf(w2.x, Xv[8],  h); h = fmaf(w2.y, Xv[9],  h);                      \
    h = fmaf(w2.z, Xv[10], h); h = fmaf(w2.w, Xv[11], h);                      \
    h = fmaf(w3.x, Xv[12], h); h = fmaf(w3.y, Xv[13], h);                      \
    h = fmaf(w3.z, Xv[14], h); h = fmaf(w3.w, Xv[15], h);                      \
    h = fmaf(w4.x, Xv[16], h); h = fmaf(w4.y, Xv[17], h);                      \
    h = fmaf(w4.z, Xv[18], h); h = fmaf(w4.w, Xv[19], h)

    float acc[7];
#pragma unroll
    for (int j = 0; j < 7; j++) acc[j] = 0.f;

    // ---- group A: j = 0..3 ----
    {
        float xf[4][20];
#pragma unroll
        for (int j = 0; j < 4; j++) BUILD_XF(xf[j]);

        for (int q = 0; q < 20; q++) {
            const float4* w0p = (const float4*)(s_wcm + q * 20);
            const float4* w1p = (const float4*)(s_wcm + 400 + q * 20);
            float4 u0 = w0p[0], u1 = w0p[1], u2 = w0p[2], u3 = w0p[3], u4 = w0p[4];
            float4 v0 = w1p[0], v1 = w1p[1], v2 = w1p[2], v3 = w1p[3], v4 = w1p[4];
            float bq = s_bcomb[q], wq = s_wfin[q];
#pragma unroll
            for (int jj = 0; jj < 4; jj++) {
                float h = bq;
                if (mrow & (1u << jj)) { DOT20(h, v0, v1, v2, v3, v4, xf[jj]); }
                else                   { DOT20(h, u0, u1, u2, u3, u4, xf[jj]); }
                acc[jj] = fmaf(wq, fmaxf(h, 0.f), acc[jj]);
            }
        }
    }

    // ---- group B: j = 4..6 ----
    {
        float xf[3][20];
#pragma unroll
        for (int j = 0; j < 3; j++) BUILD_XF(xf[j]);

        for (int q = 0; q < 20; q++) {
            const float4* w0p = (const float4*)(s_wcm + q * 20);
            const float4* w1p = (const float4*)(s_wcm + 400 + q * 20);
            float4 u0 = w0p[0], u1 = w0p[1], u2 = w0p[2], u3 = w0p[3], u4 = w0p[4];
            float4 v0 = w1p[0], v1 = w1p[1], v2 = w1p[2], v3 = w1p[3], v4 = w1p[4];
            float bq = s_bcomb[q], wq = s_wfin[q];
#pragma unroll
            for (int jj = 0; jj < 3; jj++) {
                float h = bq;
                if (mrow & (1u << (4 + jj))) { DOT20(h, v0, v1, v2, v3, v4, xf[jj]); }
                else                         { DOT20(h, u0, u1, u2, u3, u4, xf[jj]); }
                acc[4 + jj] = fmaf(wq, fmaxf(h, 0.f), acc[4 + jj]);
            }
        }
    }

    float total = 0.f;
    float bfin = s_bfin;
#pragma unroll
    for (int j = 0; j < 7; j++) total += fmaxf(acc[j] + bfin, 0.f);

    out[(size_t)bp * 8 + i] = total;
#undef BUILD_XF
#undef DOT20
}

extern "C" void kernel_launch(void* const* d_in, const int* in_sizes, int n_in,
                              void* d_out, int out_size, void* d_ws, size_t ws_size,
                              hipStream_t stream) {
    const float* feat      = (const float*)d_in[0];
    const float* emb_phase = (const float*)d_in[1];
    const float* w_veh     = (const float*)d_in[2];
    const float* b_veh     = (const float*)d_in[3];
    const float* w_line    = (const float*)d_in[4];
    const float* b_line    = (const float*)d_in[5];
    const float* emb_const = (const float*)d_in[6];
    const float* w_feat    = (const float*)d_in[7];
    const float* b_feat    = (const float*)d_in[8];
    const float* w_const   = (const float*)d_in[9];
    const float* b_const   = (const float*)d_in[10];
    const float* w_comb    = (const float*)d_in[11];
    const float* b_comb    = (const float*)d_in[12];
    const float* w_final   = (const float*)d_in[13];
    const float* b_final   = (const float*)d_in[14];
    const int*   cmask     = (const int*)d_in[15];

    int B = in_sizes[0] / 16;            // 16384
    int blocks = (B + 63) / 64;          // 256 blocks of 512 threads (8 waves = 8 phases)
    frap_fused<<<blocks, 512, 0, stream>>>(feat, emb_phase, w_veh, b_veh,
                                           w_line, b_line, emb_const, w_feat,
                                           b_feat, w_const, b_const, w_comb,
                                           b_comb, w_final, b_final, cmask,
                                           (float*)d_out, B);
}